// Round 1
// baseline (378.452 us; speedup 1.0000x reference)
//
#include <hip/hip_runtime.h>
#include <hip/hip_bf16.h>
#include <math.h>

#define NEGINF (-9000000000000000.0f)

constexpr int B_    = 8;
constexpr int N_    = 2048;
constexpr int FIN   = 256;
constexpr int FOUT  = 128;
constexpr int K1_ROWS = 16;
constexpr int TI    = 8;

// ---------------------------------------------------------------------------
// K0: Wa1[k] = sum_d W[k][d]*a[d];  Wa2[k] = sum_d W[k][d]*a[FOUT+d]
// (f1 = x . Wa1, f2 = x . Wa2 — mathematically identical to einsum on Wh)
// ---------------------------------------------------------------------------
__global__ __launch_bounds__(256) void k0_wa(const float* __restrict__ W,
                                             const float* __restrict__ a,
                                             float* __restrict__ Wa) {
    int k = threadIdx.x;  // 256 threads, one per Fin row of W
    float s1 = 0.f, s2 = 0.f;
    for (int d = 0; d < FOUT; ++d) {
        float w = W[k * FOUT + d];
        s1 += w * a[d];
        s2 += w * a[FOUT + d];
    }
    Wa[k]       = s1;
    Wa[FIN + k] = s2;
}

// ---------------------------------------------------------------------------
// K1: Wh = x @ W  (rows tiled 16 per block), plus f1/f2 per row.
// ---------------------------------------------------------------------------
__global__ __launch_bounds__(256) void k1_wh(const float* __restrict__ x,
                                             const float* __restrict__ W,
                                             const float* __restrict__ Wa,
                                             float* __restrict__ Wh,
                                             float* __restrict__ f1,
                                             float* __restrict__ f2) {
    __shared__ float xs[K1_ROWS * FIN];  // 16 KB
    const int tid = threadIdx.x;
    const long r0 = (long)blockIdx.x * K1_ROWS;  // flat row = b*N + i

    // stage 16 consecutive x rows (contiguous 16 KB) into LDS
    {
        const float4* x4  = (const float4*)(x + r0 * FIN);
        float4*       xs4 = (float4*)xs;
#pragma unroll
        for (int it = 0; it < (K1_ROWS * FIN / 4) / 256; ++it)
            xs4[tid + it * 256] = x4[tid + it * 256];
    }
    __syncthreads();

    const int d    = tid & (FOUT - 1);  // output dim 0..127
    const int half = tid >> 7;          // rows 0-7 or 8-15
    float acc[8] = {0.f, 0.f, 0.f, 0.f, 0.f, 0.f, 0.f, 0.f};
    for (int k = 0; k < FIN; ++k) {
        float w = W[k * FOUT + d];  // coalesced per wave, L1/L2 hot
#pragma unroll
        for (int q = 0; q < 8; ++q)
            acc[q] += xs[(half * 8 + q) * FIN + k] * w;  // LDS broadcast
    }
#pragma unroll
    for (int q = 0; q < 8; ++q)
        Wh[(r0 + half * 8 + q) * FOUT + d] = acc[q];

    // f1/f2: wave w reduces rows 4w..4w+3
    const int wave = tid >> 6, lane = tid & 63;
#pragma unroll
    for (int rr = 0; rr < 4; ++rr) {
        int row = wave * 4 + rr;
        float s1 = 0.f, s2 = 0.f;
        for (int k = lane; k < FIN; k += 64) {
            float xv = xs[row * FIN + k];
            s1 += xv * Wa[k];
            s2 += xv * Wa[FIN + k];
        }
#pragma unroll
        for (int o = 32; o; o >>= 1) {
            s1 += __shfl_down(s1, o);
            s2 += __shfl_down(s2, o);
        }
        if (lane == 0) {
            f1[r0 + row] = s1;
            f2[r0 + row] = s2;
        }
    }
}

// ---------------------------------------------------------------------------
// K2: fused masked-softmax attention + P@Wh + ELU. One block per 8 rows.
// b = blockIdx&7 pins each batch to one XCD for Wh L2 locality.
// LDS = exactly 64 KB (p) -> 2 blocks/CU.
// ---------------------------------------------------------------------------
__global__ __launch_bounds__(256) void k2_attn(const int* __restrict__ adj,
                                               const float* __restrict__ Wh,
                                               const float* __restrict__ f1,
                                               const float* __restrict__ f2,
                                               float* __restrict__ out) {
    __shared__ float p[TI][N_];  // 64 KB: unnormalized softmax weights

    const int tid  = threadIdx.x;
    const int b    = blockIdx.x & 7;
    const int i0   = (blockIdx.x >> 3) * TI;
    const int lane = tid & 63;
    const int wave = tid >> 6;

    const float4* f2b4 = (const float4*)(f2 + (size_t)b * N_);

    // ---- Phase A: scores + online max + exp, wave w does rows 2w, 2w+1 ----
    float sA = 1.f, sB = 1.f;  // per-wave row sums (kept in registers)
#pragma unroll
    for (int rr = 0; rr < 2; ++rr) {
        const int ti = wave * 2 + rr;
        const int i  = i0 + ti;
        const float f1i = f1[(size_t)b * N_ + i];
        const int4* arow4 = (const int4*)(adj + ((size_t)b * N_ + i) * N_);
        float4* prow4 = (float4*)&p[ti][0];

        float m = NEGINF;
        for (int j4 = lane; j4 < N_ / 4; j4 += 64) {
            int4   av = arow4[j4];
            float4 fv = f2b4[j4];
            float e0 = f1i + fv.x; e0 = (e0 >= 0.f) ? e0 : 2.f * e0; if (av.x <= 0) e0 = NEGINF;
            float e1 = f1i + fv.y; e1 = (e1 >= 0.f) ? e1 : 2.f * e1; if (av.y <= 0) e1 = NEGINF;
            float e2 = f1i + fv.z; e2 = (e2 >= 0.f) ? e2 : 2.f * e2; if (av.z <= 0) e2 = NEGINF;
            float e3 = f1i + fv.w; e3 = (e3 >= 0.f) ? e3 : 2.f * e3; if (av.w <= 0) e3 = NEGINF;
            prow4[j4] = make_float4(e0, e1, e2, e3);
            m = fmaxf(m, fmaxf(fmaxf(e0, e1), fmaxf(e2, e3)));
        }
#pragma unroll
        for (int o = 32; o; o >>= 1) m = fmaxf(m, __shfl_xor(m, o));

        float s = 0.f;
        for (int j4 = lane; j4 < N_ / 4; j4 += 64) {
            float4 pv = prow4[j4];
            pv.x = __expf(pv.x - m);
            pv.y = __expf(pv.y - m);
            pv.z = __expf(pv.z - m);
            pv.w = __expf(pv.w - m);
            prow4[j4] = pv;
            s += pv.x + pv.y + pv.z + pv.w;
        }
#pragma unroll
        for (int o = 32; o; o >>= 1) s += __shfl_xor(s, o);
        if (rr == 0) sA = s; else sB = s;
    }
    __syncthreads();

    // ---- Phase B: acc[ti][0:4] += p[ti][j] * Wh[b,j, tq*4 .. tq*4+3] ----
    const int jg = tid >> 5;  // 0..7: j-slice
    const int tq = tid & 31;  // dim quad 0..31
    float4 acc[TI];
#pragma unroll
    for (int t = 0; t < TI; ++t) acc[t] = make_float4(0.f, 0.f, 0.f, 0.f);

    const float4* WhB = (const float4*)(Wh + (size_t)b * N_ * FOUT);
    const int jend = (jg + 1) * (N_ / 8);
    for (int j = jg * (N_ / 8); j < jend; ++j) {
        float4 wv = WhB[j * (FOUT / 4) + tq];  // coalesced: 512B row per half-wave
#pragma unroll
        for (int t = 0; t < TI; ++t) {
            float pj = p[t][j];  // 2-way LDS broadcast: free
            acc[t].x += pj * wv.x;
            acc[t].y += pj * wv.y;
            acc[t].z += pj * wv.z;
            acc[t].w += pj * wv.w;
        }
    }
    __syncthreads();  // done reading p; reuse its space for reduction

    float4* red4 = (float4*)&p[0][0];  // [jg][ti][32] float4 = 32 KB
#pragma unroll
    for (int t = 0; t < TI; ++t)
        red4[(jg * TI + t) * (FOUT / 4) + tq] = acc[t];
    __syncthreads();

    // ---- Epilogue: combine 8 j-slices, divide by row sum, ELU, store ----
    // lanes 0-31 of wave w handle row 2w; lanes 32-63 row 2w+1 — exactly the
    // rows whose sums this wave holds in registers (sA/sB).
    const int ti  = tid >> 5;
    const int tq2 = tid & 31;
    float4 tot = make_float4(0.f, 0.f, 0.f, 0.f);
#pragma unroll
    for (int g = 0; g < 8; ++g) {
        float4 v = red4[(g * TI + ti) * (FOUT / 4) + tq2];
        tot.x += v.x; tot.y += v.y; tot.z += v.z; tot.w += v.w;
    }
    const float inv = 1.f / (((tid & 32) == 0) ? sA : sB);
    tot.x *= inv; tot.y *= inv; tot.z *= inv; tot.w *= inv;
    tot.x = (tot.x > 0.f) ? tot.x : expm1f(tot.x);
    tot.y = (tot.y > 0.f) ? tot.y : expm1f(tot.y);
    tot.z = (tot.z > 0.f) ? tot.z : expm1f(tot.z);
    tot.w = (tot.w > 0.f) ? tot.w : expm1f(tot.w);

    float4* out4 = (float4*)out;
    out4[((size_t)b * N_ + i0 + ti) * (FOUT / 4) + tq2] = tot;
}

// ---------------------------------------------------------------------------
extern "C" void kernel_launch(void* const* d_in, const int* in_sizes, int n_in,
                              void* d_out, int out_size, void* d_ws, size_t ws_size,
                              hipStream_t stream) {
    const float* x   = (const float*)d_in[0];
    const int*   adj = (const int*)d_in[1];
    const float* W   = (const float*)d_in[2];
    const float* a   = (const float*)d_in[3];
    float* out = (float*)d_out;

    // workspace layout (all fp32): Wh | f1 | f2 | Wa   (~8.5 MB)
    float* Wh = (float*)d_ws;
    float* f1 = Wh + (size_t)B_ * N_ * FOUT;
    float* f2 = f1 + (size_t)B_ * N_;
    float* Wa = f2 + (size_t)B_ * N_;

    hipLaunchKernelGGL(k0_wa, dim3(1), dim3(256), 0, stream, W, a, Wa);
    hipLaunchKernelGGL(k1_wh, dim3(B_ * N_ / K1_ROWS), dim3(256), 0, stream,
                       x, W, Wa, Wh, f1, f2);
    hipLaunchKernelGGL(k2_attn, dim3(B_ * N_ / TI), dim3(256), 0, stream,
                       adj, Wh, f1, f2, out);
}